// Round 6
// baseline (79.223 us; speedup 1.0000x reference)
//
#include <hip/hip_runtime.h>
#include <stdint.h>

#define NMOL 16
#define MS   4096
#define NA   32
#define NP   512
#define BM   32

typedef __attribute__((ext_vector_type(4))) float  f32x4;
typedef __attribute__((ext_vector_type(4))) unsigned int u32x4;
typedef __attribute__((ext_vector_type(8))) short  s16x8;
typedef unsigned int uint;
typedef unsigned short ushort;

// ws layout
#define WS_DMF_OFF   0u
#define WS_DMF_SZ    (16u*512u*512u*2u)
#define WS_M2A_OFF   (WS_DMF_OFF + WS_DMF_SZ)
#define WS_M2A_SZ    (16u*512u*4u)
#define WS_M2B_OFF   (WS_M2A_OFF + WS_M2A_SZ)
#define WS_M2B_SZ    (16u*512u*4u)
#define WS_ALPH_OFF  (WS_M2B_OFF + WS_M2B_SZ)

// WFN symmetry table packed px | py<<4 | pz<<8
__device__ __constant__ uint c_pw[20] = {
  0x000,
  0x001, 0x010, 0x100,
  0x002, 0x020, 0x200, 0x011, 0x101, 0x110,
  0x003, 0x030, 0x300, 0x012, 0x102, 0x120, 0x021, 0x201, 0x210, 0x111
};

__device__ __forceinline__ ushort f2bf(float f) {
  uint u = __float_as_uint(f);
  u = u + 0x7fffu + ((u >> 16) & 1u);   // RNE
  return (ushort)(u >> 16);
}
__device__ __forceinline__ float bf2f(ushort b) {
  return __uint_as_float(((uint)b) << 16);
}
__device__ __forceinline__ void ld8f(const float* p, float* o) {
  f32x4 a = *(const f32x4*)p, b = *(const f32x4*)(p + 4);
  o[0]=a[0];o[1]=a[1];o[2]=a[2];o[3]=a[3];o[4]=b[0];o[5]=b[1];o[6]=b[2];o[7]=b[3];
}
__device__ __forceinline__ void ld8u(const uint* p, uint* o) {
  u32x4 a = *(const u32x4*)p, b = *(const u32x4*)(p + 4);
  o[0]=a[0];o[1]=a[1];o[2]=a[2];o[3]=a[3];o[4]=b[0];o[5]=b[1];o[6]=b[2];o[7]=b[3];
}

// ---- dm fp32 [n][p][q] -> dmF bf16 fragment-packed [n][Q(32)][kblk(16)][lane(64)][8]
// dmF[..][lane][j] = dm[n][ p = kblk*32 + (lane>>4)*8 + j ][ q = Q*16 + (lane&15) ]
__global__ void dm_pack(const float* __restrict__ dm, short* __restrict__ dmF) {
  __shared__ float tile[NP * 16];   // 32 KB
  const int Q = blockIdx.x, n = blockIdx.y;
  const float* src = dm + (size_t)n * NP * NP + Q * 16;
#pragma unroll
  for (int i = 0; i < 32; ++i) {
    int e = threadIdx.x + 256 * i;
    int p = e >> 4, c = e & 15;
    tile[e] = src[(size_t)p * NP + c];
  }
  __syncthreads();
  short* dst = dmF + ((size_t)(n * 32 + Q) * 16) * 512;
#pragma unroll
  for (int i = 0; i < 4; ++i) {
    int v = threadIdx.x + 256 * i;
    int kblk = v >> 6, l = v & 63;
    int p0 = kblk * 32 + ((l >> 4) << 3);
    int col = l & 15;
    s16x8 o;
#pragma unroll
    for (int j = 0; j < 8; ++j) o[j] = (short)f2bf(tile[(p0 + j) * 16 + col]);
    *(s16x8*)(dst + (size_t)v * 8) = o;
  }
}

// ---- one-shot prep: bake LDS half-offset codes for the 3 monomial slots.
// comp table row (c*4+ax) at byte 32768 + row*64 -> half-offset 16384 + row*32.
// ones-row half-offset = 0 (basis region smem[0..64) holds f16 1.0 in phase 1).
// m2a = h0 | h1<<16 ; m2b = h2 | c<<16 ; alphaS = -alpha*log2(e)  (invalid -> exp ~ 0)
__global__ void prep_pack(const int* __restrict__ centers, const int* __restrict__ sym,
                          const float* __restrict__ expg,
                          uint* __restrict__ m2a, uint* __restrict__ m2b,
                          float* __restrict__ alphaS) {
  int i = blockIdx.x * 256 + threadIdx.x;     // 8192 total
  int craw = centers[i], s = sym[i];
  bool valid = (craw >= 0);
  uint c = (uint)((valid ? craw : 0) & (NA - 1));
  int si = valid ? s : 0;
  si = (si >= 0 && si < 20) ? si : 0;
  uint pw = c_pw[si];
  uint h[3]; int k = 0;
#pragma unroll
  for (uint ax = 0; ax < 3; ++ax) {
    uint e = (pw >> (4 * ax)) & 15u;
    for (uint r = 0; r < e; ++r) if (k < 3) h[k++] = 16384u + (c * 4u + ax) * 32u;
  }
  while (k < 3) h[k++] = 0u;                  // ones-row
  if (!valid) { h[0] = h[1] = h[2] = 0u; }
  m2a[i] = h[0] | (h[1] << 16);
  m2b[i] = h[2] | (c << 16);
  alphaS[i] = (valid ? -expg[i] : -1e5f) * 1.44269504088896f;
}

// ---------------- fused basis + GEMM + quadratic-form, BM=32, 8 waves ------------
// LDS map (40960 B exact -> 4 blocks/CU, 32 waves/CU):
//   [0, 32768)      phase1: ones row [0,64) | phase2: basis bf16 [32 rows][1KB] swz
//                   final: rho_buf f32[8][32]
//   [32768, 40960)  comp table f16 [c(32)][x,y,z,r2][m^swz (32)]   (8 KB)
__launch_bounds__(512, 8)
__global__ void wfn_fused8(const float* __restrict__ dv,
                           const uint* __restrict__ m2aG,
                           const uint* __restrict__ m2bG,
                           const float* __restrict__ alG,
                           const short* __restrict__ dmF,
                           float* __restrict__ out) {
  __shared__ __align__(16) char smem[40960];

  const int t = threadIdx.x;
  // XCD-aware swizzle (bijective, 2048 blocks): 2 molecules per XCD -> dmF L2-resident
  const int bid = ((blockIdx.x & 7) << 8) + (blockIdx.x >> 3);
  const int n  = bid >> 7;
  const int m0 = (bid & 127) * BM;

  // ---------------- phase 1a: ones row + f16 component/r2 table ----------------
  if (t < 16) *(uint*)(smem + t * 4) = 0x3C003C00u;   // 32 x f16(1.0)
  {
    const float* dvg = dv + (size_t)(n * MS + m0) * (NA * 3);
#pragma unroll
    for (int k = 0; k < 2; ++k) {
      int idx = t + 512 * k;              // 1024 (m,c) pairs
      int m = idx >> 5, c = idx & 31;
      const float* p = dvg + (m * NA + c) * 3;
      float x = p[0], y = p[1], z = p[2];
      float r2 = fmaf(x, x, fmaf(y, y, z * z));
      int ms = m ^ ((c << 1) & 31);       // XOR swizzle: spreads banks on build & read
      char* rowb = smem + 32768 + c * 256 + ms * 2;
      *(_Float16*)(rowb)       = (_Float16)x;
      *(_Float16*)(rowb + 64)  = (_Float16)y;
      *(_Float16*)(rowb + 128) = (_Float16)z;
      *(_Float16*)(rowb + 192) = (_Float16)r2;
    }
  }
  __syncthreads();

  // ---------------- phase 1b: basis -> registers ----------------
  const int mloc = t & 31;          // row within tile
  const int pg   = t >> 5;          // 0..15, p-group (half-wave-uniform)
  const uint*  mA = m2aG + n * NP + pg * 32;
  const uint*  mB = m2bG + n * NP + pg * 32;
  const float* aG = alG  + n * NP + pg * 32;

  s16x8 bfr[4];
#pragma unroll
  for (int i = 0; i < 4; ++i) {
    uint a8[8], b8[8]; float al8[8];
    ld8u(mA + i * 8, a8); ld8u(mB + i * 8, b8); ld8f(aG + i * 8, al8);
    uint w[4];
#pragma unroll
    for (int jp = 0; jp < 4; ++jp) {
      float vp0 = 0.f, vp1 = 0.f;
#pragma unroll
      for (int jo = 0; jo < 2; ++jo) {
        int j = jp * 2 + jo;
        uint wa = a8[j], wb = b8[j];
        uint c  = wb >> 16;
        uint lb = (uint)(mloc ^ (int)((c << 1) & 31u)) << 1;
        float xv = (float)*(const _Float16*)(smem + (((wa & 0xFFFFu) << 1) + lb));
        float yv = (float)*(const _Float16*)(smem + (((wa >> 16) << 1) + lb));
        float zv = (float)*(const _Float16*)(smem + (((wb & 0xFFFFu) << 1) + lb));
        float r2 = (float)*(const _Float16*)(smem + (32768u + c * 256u + 192u + lb));
        float arg = al8[j] * r2;
        float e;
        asm("v_exp_f32 %0, %1" : "=v"(e) : "v"(arg));
        float val = xv * yv * zv * e;
        if (jo == 0) vp0 = val; else vp1 = val;
      }
      asm("v_cvt_pk_bf16_f32 %0, %1, %2" : "=v"(w[jp]) : "v"(vp0), "v"(vp1));
    }
    s16x8 f; uint* fp = (uint*)&f;
    fp[0] = w[0]; fp[1] = w[1]; fp[2] = w[2]; fp[3] = w[3];
    bfr[i] = f;
  }
  __syncthreads();   // all table/ones reads done before basis overwrites region A

  // write basis tile, slot XOR-swizzled by (row&7)
#pragma unroll
  for (int i = 0; i < 4; ++i) {
    int slot = (pg * 4 + i) ^ (mloc & 7);
    *(s16x8*)(smem + mloc * 1024 + (slot << 4)) = bfr[i];
  }
  __syncthreads();   // basis visible to all waves

  // ---------------- barrier-free MFMA GEMM + fused dot ----------------
  const int lane = t & 63, wv = t >> 6, li = lane & 15, kg = lane >> 4;
  const uint aswz = (uint)(li & 7);  // (row = rf*16+li) & 7 == li & 7
  const short* dmFn = dmF + (size_t)n * (32 * 16 * 512);

  f32x4 acc[2][4];
#pragma unroll
  for (int rf = 0; rf < 2; ++rf)
#pragma unroll
    for (int qf = 0; qf < 4; ++qf)
      acc[rf][qf] = (f32x4){0.f, 0.f, 0.f, 0.f};

  const short* bptr[4];
#pragma unroll
  for (int qf = 0; qf < 4; ++qf)
    bptr[qf] = dmFn + ((size_t)((wv * 4 + qf) * 16) * 512) + lane * 8;

#pragma unroll 2
  for (int kblk = 0; kblk < 16; ++kblk) {
    s16x8 bf[4], af[2];
#pragma unroll
    for (int qf = 0; qf < 4; ++qf)
      bf[qf] = *(const s16x8*)(bptr[qf] + kblk * 512);   // 1KB coalesced, L2-hot
    const uint aoff = (((uint)(kblk * 4 + kg)) ^ aswz) << 4;
#pragma unroll
    for (int rf = 0; rf < 2; ++rf)
      af[rf] = *(const s16x8*)(smem + (rf * 16 + li) * 1024 + aoff);
#pragma unroll
    for (int rf = 0; rf < 2; ++rf)
#pragma unroll
      for (int qf = 0; qf < 4; ++qf)
        acc[rf][qf] = __builtin_amdgcn_mfma_f32_16x16x32_bf16(
            af[rf], bf[qf], acc[rf][qf], 0, 0, 0);
  }

  // fused dot: part[m] = sum_q Y[m,q] * basis[m,q]
  float part[8];
#pragma unroll
  for (int rf = 0; rf < 2; ++rf) {
#pragma unroll
    for (int jj = 0; jj < 4; ++jj) {
      int m = rf * 16 + kg * 4 + jj;          // D layout: row=(lane>>4)*4+reg
      uint rb  = (uint)m * 1024u;
      uint msw = (uint)(m & 7);
      float a = 0.0f;
#pragma unroll
      for (int qf = 0; qf < 4; ++qf) {
        int q = wv * 64 + qf * 16 + li;       // D col = lane&15
        uint addr = rb + ((((uint)(q >> 3)) ^ msw) << 4) + (uint)((q & 7) << 1);
        float bv = bf2f(*(const ushort*)(smem + addr));
        a = fmaf(acc[rf][qf][jj], bv, a);
      }
      part[rf * 4 + jj] = a;
    }
  }

  // ---------------- reduce + store (atomic-free, deterministic) ----------------
  __syncthreads();   // all basis reads done before rbuf overwrites row 0
#pragma unroll
  for (int x = 0; x < 8; ++x) {
    float v = part[x];
    v += __shfl_xor(v, 1);
    v += __shfl_xor(v, 2);
    v += __shfl_xor(v, 4);
    v += __shfl_xor(v, 8);
    part[x] = v;
  }
  float* rbuf = (float*)smem;
  if (li == 0) {
#pragma unroll
    for (int rf = 0; rf < 2; ++rf)
#pragma unroll
      for (int jj = 0; jj < 4; ++jj)
        rbuf[wv * 32 + rf * 16 + kg * 4 + jj] = part[rf * 4 + jj];
  }
  __syncthreads();
  if (t < BM) {
    float s = 0.0f;
#pragma unroll
    for (int w = 0; w < 8; ++w) s += rbuf[w * 32 + t];
    out[(size_t)n * MS + m0 + t] = s;
  }
}

extern "C" void kernel_launch(void* const* d_in, const int* in_sizes, int n_in,
                              void* d_out, int out_size, void* d_ws, size_t ws_size,
                              hipStream_t stream) {
  const float* dv      = (const float*)d_in[0];
  const int*   centers = (const int*)d_in[1];
  const float* expg    = (const float*)d_in[2];
  const int*   sym     = (const int*)d_in[3];
  const float* dm      = (const float*)d_in[4];
  float* out = (float*)d_out;

  char* ws = (char*)d_ws;
  short* dmF    = (short*)(ws + WS_DMF_OFF);
  uint*  m2a    = (uint*)(ws + WS_M2A_OFF);
  uint*  m2b    = (uint*)(ws + WS_M2B_OFF);
  float* alphaS = (float*)(ws + WS_ALPH_OFF);

  dm_pack<<<dim3(32, NMOL), 256, 0, stream>>>(dm, dmF);
  prep_pack<<<dim3(32), 256, 0, stream>>>(centers, sym, expg, m2a, m2b, alphaS);
  wfn_fused8<<<dim3(NMOL * (MS / BM)), 512, 0, stream>>>(dv, m2a, m2b, alphaS, dmF, out);
}

// Round 7
// 56.886 us; speedup vs baseline: 1.3927x; 1.3927x over previous
//
#include <hip/hip_runtime.h>
#include <stdint.h>

#define NMOL 16
#define MS   4096
#define NA   32
#define NP   512
#define BM   64
#define TBL  65536u

typedef __attribute__((ext_vector_type(4))) float  f32x4;
typedef __attribute__((ext_vector_type(4))) unsigned int u32x4;
typedef __attribute__((ext_vector_type(2))) unsigned int u32x2;
typedef __attribute__((ext_vector_type(8))) short  s16x8;
typedef unsigned int uint;
typedef unsigned short ushort;

// ws layout
#define WS_DMF_OFF   0u
#define WS_DMF_SZ    (16u*512u*512u*2u)
#define WS_M2A_OFF   (WS_DMF_OFF + WS_DMF_SZ)
#define WS_M2A_SZ    (16u*512u*4u)
#define WS_M2B_OFF   (WS_M2A_OFF + WS_M2A_SZ)
#define WS_M2B_SZ    (16u*512u*4u)
#define WS_ALPH_OFF  (WS_M2B_OFF + WS_M2B_SZ)

// WFN symmetry table packed px | py<<4 | pz<<8
__device__ __constant__ uint c_pw[20] = {
  0x000,
  0x001, 0x010, 0x100,
  0x002, 0x020, 0x200, 0x011, 0x101, 0x110,
  0x003, 0x030, 0x300, 0x012, 0x102, 0x120, 0x021, 0x201, 0x210, 0x111
};

__device__ __forceinline__ ushort f2bf(float f) {
  uint u = __float_as_uint(f);
  u = u + 0x7fffu + ((u >> 16) & 1u);   // RNE
  return (ushort)(u >> 16);
}
__device__ __forceinline__ float bflo(uint u) { return __uint_as_float(u << 16); }
__device__ __forceinline__ float bfhi(uint u) { return __uint_as_float(u & 0xFFFF0000u); }
__device__ __forceinline__ float cvt16lo(uint u) {
  float r; asm("v_cvt_f32_f16 %0, %1" : "=v"(r) : "v"(u)); return r;
}
__device__ __forceinline__ float cvt16hi(uint u) {
  uint s = u >> 16; float r; asm("v_cvt_f32_f16 %0, %1" : "=v"(r) : "v"(s)); return r;
}
__device__ __forceinline__ uint pkmul(uint a, uint b) {
  uint r; asm("v_pk_mul_f16 %0, %1, %2" : "=v"(r) : "v"(a), "v"(b)); return r;
}
__device__ __forceinline__ s16x8 mkfrag(u32x2 lo, u32x2 hi) {
  union { uint u[4]; s16x8 v; } x;
  x.u[0] = lo[0]; x.u[1] = lo[1]; x.u[2] = hi[0]; x.u[3] = hi[1];
  return x.v;
}

// ---- dm fp32 [n][p][q] -> dmF bf16 fragment-packed [n][Q(32)][kblk(16)][lane(64)][8]
// dmF[..][lane][j] = dm[n][ p = kblk*32 + (lane>>4)*8 + j ][ q = Q*16 + (lane&15) ]
__global__ void dm_pack(const float* __restrict__ dm, short* __restrict__ dmF) {
  __shared__ float tile[NP * 16];   // 32 KB
  const int Q = blockIdx.x, n = blockIdx.y;
  const float* src = dm + (size_t)n * NP * NP + Q * 16;
#pragma unroll
  for (int i = 0; i < 32; ++i) {
    int e = threadIdx.x + 256 * i;
    int p = e >> 4, c = e & 15;
    tile[e] = src[(size_t)p * NP + c];
  }
  __syncthreads();
  short* dst = dmF + ((size_t)(n * 32 + Q) * 16) * 512;
#pragma unroll
  for (int i = 0; i < 4; ++i) {
    int v = threadIdx.x + 256 * i;
    int kblk = v >> 6, l = v & 63;
    int p0 = kblk * 32 + ((l >> 4) << 3);
    int col = l & 15;
    s16x8 o;
#pragma unroll
    for (int j = 0; j < 8; ++j) o[j] = (short)f2bf(tile[(p0 + j) * 16 + col]);
    *(s16x8*)(dst + (size_t)v * 8) = o;
  }
}

// ---- one-shot prep: per primitive pack 3 monomial row offsets (rel table base),
// degree d, and alphaS = -alpha*log2(e).
// row(c, ax) byte offset = c*512 + ax*128  (< 16384, 14 bits)
// m2a = h0 | h1<<16 ; m2b = h2 | d<<14 | c<<16
__global__ void prep_pack(const int* __restrict__ centers, const int* __restrict__ sym,
                          const float* __restrict__ expg,
                          uint* __restrict__ m2a, uint* __restrict__ m2b,
                          float* __restrict__ alphaS) {
  int i = blockIdx.x * 256 + threadIdx.x;     // 8192 total
  int craw = centers[i], s = sym[i];
  bool valid = (craw >= 0);
  uint c = (uint)((valid ? craw : 0) & (NA - 1));
  int si = valid ? s : 0;
  si = (si >= 0 && si < 20) ? si : 0;
  uint pw = c_pw[si];
  uint px = pw & 15u, py = (pw >> 4) & 15u, pz = (pw >> 8) & 15u;
  uint d = px + py + pz;
  uint h[3]; int k = 0;
#pragma unroll
  for (uint ax = 0; ax < 3; ++ax) {
    uint e = (pw >> (4 * ax)) & 15u;
    for (uint r = 0; r < e; ++r) if (k < 3) h[k++] = c * 512u + ax * 128u;
  }
  while (k < 3) h[k++] = c * 512u;            // harmless filler row (unused when d small)
  m2a[i] = h[0] | (h[1] << 16);
  m2b[i] = h[2] | (d << 14) | (c << 16);
  alphaS[i] = (valid ? -expg[i] : -1e5f) * 1.44269504088896f;
}

// ---------------- fused basis + GEMM + quadratic-form, BM=64, 8 waves ------------
// LDS map (81920 B exact -> 2 blocks/CU):
//   [0, 65536)      basis bf16 in [4p][16m] tiles, tile order [mblk(4)][kblk(16)][par(2)][kg(4)]
//                   element (p,m): tile(m>>4, p>>5, (p>>2)&1, (p&31)>>3), row p&3, col m&15
//                   final: rho_buf f32[8][64] reuses [0,2KB)
//   [65536, 81920)  comp table f16 [c(32)][x,y,z,r2][8 chunks], chunk j stored at j^(c&7)
__launch_bounds__(512, 4)
__global__ void wfn_fused8(const float* __restrict__ dv,
                           const uint* __restrict__ m2aG,
                           const uint* __restrict__ m2bG,
                           const float* __restrict__ alG,
                           const short* __restrict__ dmF,
                           float* __restrict__ out) {
  __shared__ __align__(16) char smem[81920];
  const int t = threadIdx.x;
  // XCD-aware swizzle (bijective, 1024 blocks)
  const int bid = ((blockIdx.x & 7) << 7) + (blockIdx.x >> 3);
  const int n  = bid >> 6;
  const int m0 = (bid & 63) * BM;

  // ---------------- phase 1a: f16 component/r2 table ----------------
  {
    const float* dvg = dv + (size_t)(n * MS + m0) * (NA * 3);
#pragma unroll
    for (int k = 0; k < 4; ++k) {
      int idx = t + 512 * k;              // 2048 (m,c) pairs
      int m = idx >> 5, c = idx & 31;
      const float* p = dvg + (m * NA + c) * 3;
      float x = p[0], y = p[1], z = p[2];
      float r2 = fmaf(x, x, fmaf(y, y, z * z));
      uint base = TBL + (uint)c * 512u
                + ((uint)((m >> 3) ^ (c & 7)) << 4) + (uint)((m & 7) << 1);
      *(_Float16*)(smem + base)       = (_Float16)x;
      *(_Float16*)(smem + base + 128) = (_Float16)y;
      *(_Float16*)(smem + base + 256) = (_Float16)z;
      *(_Float16*)(smem + base + 384) = (_Float16)r2;
    }
  }
  __syncthreads();

  // ---------------- phase 1b: thread owns p = t, computes 64 m values ----------------
  {
    const int p = t;
    const uint ma = m2aG[n * NP + p], mb = m2bG[n * NP + p];
    const float al = alG[n * NP + p];
    const uint h0 = ma & 0xFFFFu, h1 = ma >> 16;
    const uint h2 = mb & 0x3FFFu;
    const uint d  = (mb >> 14) & 3u;
    const uint cs = (h0 >> 9) & 7u;
    const uint rh = (h0 & 0xFE00u) + 384u;
    const bool ge2 = (d >= 2), eq3 = (d == 3), eq0 = (d == 0);
    const uint wbase = ((uint)(p >> 5) << 10) + (((uint)(p >> 2) & 1u) << 9)
                     + ((((uint)p & 31u) >> 3) << 7) + (((uint)p & 3u) << 5);
#pragma unroll
    for (int j = 0; j < 8; ++j) {
      uint off = (uint)((j ^ (int)cs) << 4);
      u32x4 q0 = *(const u32x4*)(smem + TBL + h0 + off);
      u32x4 q1 = *(const u32x4*)(smem + TBL + h1 + off);
      u32x4 q2 = *(const u32x4*)(smem + TBL + h2 + off);
      u32x4 qr = *(const u32x4*)(smem + TBL + rh + off);
      uint res[4];
#pragma unroll
      for (int w = 0; w < 4; ++w) {
        uint m_ = q0[w];
        uint t1 = pkmul(m_, q1[w]);  m_ = ge2 ? t1 : m_;
        uint t2 = pkmul(m_, q2[w]);  m_ = eq3 ? t2 : m_;
        m_ = eq0 ? 0x3C003C00u : m_;
        float r2l = cvt16lo(qr[w]), r2h = cvt16hi(qr[w]);
        float a0 = al * r2l, a1 = al * r2h;
        float e0, e1;
        asm("v_exp_f32 %0, %1" : "=v"(e0) : "v"(a0));
        asm("v_exp_f32 %0, %1" : "=v"(e1) : "v"(a1));
        float v0 = cvt16lo(m_) * e0, v1 = cvt16hi(m_) * e1;
        asm("v_cvt_pk_bf16_f32 %0, %1, %2" : "=v"(res[w]) : "v"(v0), "v"(v1));
      }
      *(u32x4*)(smem + wbase + ((uint)(j >> 1) << 14) + ((uint)(j & 1) << 4))
          = *(u32x4*)res;
    }
  }
  __syncthreads();   // basis tiles visible to all waves

  // ---------------- barrier-free MFMA GEMM (tr-read A-frags) + fused dot ----------
  const int lane = t & 63, wv = t >> 6, li = lane & 15, kg = lane >> 4;
  const uint lane8 = (uint)lane << 3;
  const short* dmFn = dmF + (size_t)n * (32 * 16 * 512);

  f32x4 acc[4][4];
#pragma unroll
  for (int rf = 0; rf < 4; ++rf)
#pragma unroll
    for (int qf = 0; qf < 4; ++qf)
      acc[rf][qf] = (f32x4){0.f, 0.f, 0.f, 0.f};

  const short* bptr[4];
#pragma unroll
  for (int qf = 0; qf < 4; ++qf)
    bptr[qf] = dmFn + ((size_t)((wv * 4 + qf) * 16) * 512) + lane * 8;

#pragma unroll 2
  for (int kblk = 0; kblk < 16; ++kblk) {
    s16x8 bf[4];
#pragma unroll
    for (int qf = 0; qf < 4; ++qf)
      bf[qf] = *(const s16x8*)(bptr[qf] + kblk * 512);   // 1KB coalesced, L2-hot
    uint ak = lane8 + ((uint)kblk << 10);
    u32x2 l0, g0, l1, g1, l2, g2, l3, g3;
    asm volatile("ds_read_b64_tr_b16 %0, %1 offset:0"     : "=v"(l0) : "v"(ak));
    asm volatile("ds_read_b64_tr_b16 %0, %1 offset:512"   : "=v"(g0) : "v"(ak));
    asm volatile("ds_read_b64_tr_b16 %0, %1 offset:16384" : "=v"(l1) : "v"(ak));
    asm volatile("ds_read_b64_tr_b16 %0, %1 offset:16896" : "=v"(g1) : "v"(ak));
    asm volatile("ds_read_b64_tr_b16 %0, %1 offset:32768" : "=v"(l2) : "v"(ak));
    asm volatile("ds_read_b64_tr_b16 %0, %1 offset:33280" : "=v"(g2) : "v"(ak));
    asm volatile("ds_read_b64_tr_b16 %0, %1 offset:49152" : "=v"(l3) : "v"(ak));
    asm volatile("ds_read_b64_tr_b16 %0, %1 offset:49664" : "=v"(g3) : "v"(ak));
    asm volatile("s_waitcnt lgkmcnt(0)");
    __builtin_amdgcn_sched_barrier(0);
    s16x8 af[4];
    af[0] = mkfrag(l0, g0); af[1] = mkfrag(l1, g1);
    af[2] = mkfrag(l2, g2); af[3] = mkfrag(l3, g3);
#pragma unroll
    for (int rf = 0; rf < 4; ++rf)
#pragma unroll
      for (int qf = 0; qf < 4; ++qf)
        acc[rf][qf] = __builtin_amdgcn_mfma_f32_16x16x32_bf16(
            af[rf], bf[qf], acc[rf][qf], 0, 0, 0);
  }

  // fused dot: part[m] = sum_q Y[m,q] * basis[m,q]; one b64 per (rf,qf) covers jj=0..3
  float part[16];
#pragma unroll
  for (int x = 0; x < 16; ++x) part[x] = 0.0f;
  uint qp[4];
#pragma unroll
  for (int qf = 0; qf < 4; ++qf) {
    int q = wv * 64 + qf * 16 + li;
    qp[qf] = ((uint)(q >> 5) << 10) + (((uint)(q >> 2) & 1u) << 9)
           + (((uint)(q & 31) >> 3) << 7) + ((uint)(q & 3) << 5) + ((uint)kg << 3);
  }
#pragma unroll
  for (int rf = 0; rf < 4; ++rf) {
#pragma unroll
    for (int qf = 0; qf < 4; ++qf) {
      u32x2 dq = *(const u32x2*)(smem + ((uint)rf << 14) + qp[qf]);
      part[rf * 4 + 0] = fmaf(acc[rf][qf][0], bflo(dq[0]), part[rf * 4 + 0]);
      part[rf * 4 + 1] = fmaf(acc[rf][qf][1], bfhi(dq[0]), part[rf * 4 + 1]);
      part[rf * 4 + 2] = fmaf(acc[rf][qf][2], bflo(dq[1]), part[rf * 4 + 2]);
      part[rf * 4 + 3] = fmaf(acc[rf][qf][3], bfhi(dq[1]), part[rf * 4 + 3]);
    }
  }

  // ---------------- reduce + store (atomic-free, deterministic) ----------------
  __syncthreads();   // all basis reads done before rbuf overwrites tiles
#pragma unroll
  for (int x = 0; x < 16; ++x) {
    float v = part[x];
    v += __shfl_xor(v, 1);
    v += __shfl_xor(v, 2);
    v += __shfl_xor(v, 4);
    v += __shfl_xor(v, 8);
    part[x] = v;
  }
  float* rbuf = (float*)smem;
  if (li == 0) {
#pragma unroll
    for (int rf = 0; rf < 4; ++rf)
#pragma unroll
      for (int jj = 0; jj < 4; ++jj)
        rbuf[wv * 64 + rf * 16 + kg * 4 + jj] = part[rf * 4 + jj];
  }
  __syncthreads();
  if (t < BM) {
    float s = 0.0f;
#pragma unroll
    for (int w = 0; w < 8; ++w) s += rbuf[w * 64 + t];
    out[(size_t)n * MS + m0 + t] = s;
  }
}

extern "C" void kernel_launch(void* const* d_in, const int* in_sizes, int n_in,
                              void* d_out, int out_size, void* d_ws, size_t ws_size,
                              hipStream_t stream) {
  const float* dv      = (const float*)d_in[0];
  const int*   centers = (const int*)d_in[1];
  const float* expg    = (const float*)d_in[2];
  const int*   sym     = (const int*)d_in[3];
  const float* dm      = (const float*)d_in[4];
  float* out = (float*)d_out;

  char* ws = (char*)d_ws;
  short* dmF    = (short*)(ws + WS_DMF_OFF);
  uint*  m2a    = (uint*)(ws + WS_M2A_OFF);
  uint*  m2b    = (uint*)(ws + WS_M2B_OFF);
  float* alphaS = (float*)(ws + WS_ALPH_OFF);

  dm_pack<<<dim3(32, NMOL), 256, 0, stream>>>(dm, dmF);
  prep_pack<<<dim3(32), 256, 0, stream>>>(centers, sym, expg, m2a, m2b, alphaS);
  wfn_fused8<<<dim3(NMOL * (MS / BM)), 512, 0, stream>>>(dv, m2a, m2b, alphaS, dmF, out);
}

// Round 8
// 51.918 us; speedup vs baseline: 1.5259x; 1.0957x over previous
//
#include <hip/hip_runtime.h>
#include <stdint.h>

#define NMOL 16
#define MS   4096
#define NA   32
#define NP   512
#define BM   64
#define TBL  65536u

typedef __attribute__((ext_vector_type(4))) float  f32x4;
typedef __attribute__((ext_vector_type(4))) unsigned int u32x4;
typedef __attribute__((ext_vector_type(2))) unsigned int u32x2;
typedef __attribute__((ext_vector_type(8))) short  s16x8;
typedef unsigned int uint;
typedef unsigned short ushort;

// ws layout
#define WS_DMF_OFF   0u
#define WS_DMF_SZ    (16u*512u*512u*2u)
#define WS_M2A_OFF   (WS_DMF_OFF + WS_DMF_SZ)
#define WS_M2A_SZ    (16u*512u*4u)
#define WS_M2B_OFF   (WS_M2A_OFF + WS_M2A_SZ)
#define WS_M2B_SZ    (16u*512u*4u)
#define WS_ALPH_OFF  (WS_M2B_OFF + WS_M2B_SZ)

// WFN symmetry table packed px | py<<4 | pz<<8
__device__ __constant__ uint c_pw[20] = {
  0x000,
  0x001, 0x010, 0x100,
  0x002, 0x020, 0x200, 0x011, 0x101, 0x110,
  0x003, 0x030, 0x300, 0x012, 0x102, 0x120, 0x021, 0x201, 0x210, 0x111
};

__device__ __forceinline__ ushort f2bf(float f) {
  uint u = __float_as_uint(f);
  u = u + 0x7fffu + ((u >> 16) & 1u);   // RNE
  return (ushort)(u >> 16);
}
__device__ __forceinline__ float bflo(uint u) { return __uint_as_float(u << 16); }
__device__ __forceinline__ float bfhi(uint u) { return __uint_as_float(u & 0xFFFF0000u); }
__device__ __forceinline__ float cvt16lo(uint u) {
  float r; asm("v_cvt_f32_f16 %0, %1" : "=v"(r) : "v"(u)); return r;
}
__device__ __forceinline__ float cvt16hi(uint u) {
  uint s = u >> 16; float r; asm("v_cvt_f32_f16 %0, %1" : "=v"(r) : "v"(s)); return r;
}
__device__ __forceinline__ uint pkmul(uint a, uint b) {
  uint r; asm("v_pk_mul_f16 %0, %1, %2" : "=v"(r) : "v"(a), "v"(b)); return r;
}
__device__ __forceinline__ s16x8 mkfrag(u32x2 lo, u32x2 hi) {
  union { uint u[4]; s16x8 v; } x;
  x.u[0] = lo[0]; x.u[1] = lo[1]; x.u[2] = hi[0]; x.u[3] = hi[1];
  return x.v;
}

// ---- dm fp32 [n][p][q] -> W' = symmetrized upper-tri, bf16 fragment-packed
//      W'[p][q] = dm[p][q]+dm[q][p] (p<q) ; dm[p][p] (p==q) ; 0 (p>q)
// dmF[n][Q(32)][kblk(16)][lane(64)][8]: dmF[..][l][j] = W'[kblk*32+(l>>4)*8+j][Q*16+(l&15)]
// Also folds the one-shot meta prep (blocks with n==0).
__global__ void dm_pack(const float* __restrict__ dm, short* __restrict__ dmF,
                        const int* __restrict__ centers, const int* __restrict__ sym,
                        const float* __restrict__ expg,
                        uint* __restrict__ m2a, uint* __restrict__ m2b,
                        float* __restrict__ alphaS) {
  __shared__ float tile[NP * 16];          // dm[:, Qcols]   32 KB
  __shared__ float tileT[16 * (NP + 2)];   // dm[Qrows, :]   32.1 KB (padded rows)
  const int Q = blockIdx.x, n = blockIdx.y;
  const int t = threadIdx.x;
  const float* base = dm + (size_t)n * NP * NP;
  const float* src  = base + Q * 16;
#pragma unroll
  for (int i = 0; i < 32; ++i) {
    int e = t + 256 * i;
    int p = e >> 4, c = e & 15;
    tile[e] = src[(size_t)p * NP + c];
  }
  const float* srcT = base + (size_t)(Q * 16) * NP;
#pragma unroll
  for (int i = 0; i < 32; ++i) {
    int e = t + 256 * i;            // qq = e>>9, p = e&511
    tileT[(e >> 9) * (NP + 2) + (e & 511)] = srcT[e];
  }
  if (n == 0) {   // one-shot meta prep: this block covers primitives [Q*256, Q*256+256)
    int i = Q * 256 + t;
    int craw = centers[i], s = sym[i];
    bool valid = (craw >= 0);
    uint c = (uint)((valid ? craw : 0) & (NA - 1));
    int si = valid ? s : 0;
    si = (si >= 0 && si < 20) ? si : 0;
    uint pw = c_pw[si];
    uint d = (pw & 15u) + ((pw >> 4) & 15u) + ((pw >> 8) & 15u);
    uint h[3]; int k = 0;
#pragma unroll
    for (uint ax = 0; ax < 3; ++ax) {
      uint e = (pw >> (4 * ax)) & 15u;
      for (uint r = 0; r < e; ++r) if (k < 3) h[k++] = c * 512u + ax * 128u;
    }
    while (k < 3) h[k++] = c * 512u;
    m2a[i] = h[0] | (h[1] << 16);
    m2b[i] = h[2] | (d << 14) | (c << 16);
    alphaS[i] = (valid ? -expg[i] : -1e5f) * 1.44269504088896f;
  }
  __syncthreads();
  short* dst = dmF + ((size_t)(n * 32 + Q) * 16) * 512;
#pragma unroll
  for (int i = 0; i < 4; ++i) {
    int v = t + 256 * i;
    int kblk = v >> 6, l = v & 63;
    int p0 = kblk * 32 + ((l >> 4) << 3);
    int col = l & 15;
    int q = Q * 16 + col;
    s16x8 o;
#pragma unroll
    for (int j = 0; j < 8; ++j) {
      int p = p0 + j;
      float w = 0.0f;
      if (p < q)       w = tile[p * 16 + col] + tileT[col * (NP + 2) + p];
      else if (p == q) w = tile[p * 16 + col];
      o[j] = (short)f2bf(w);
    }
    *(s16x8*)(dst + (size_t)v * 8) = o;
  }
}

// ---------------- fused basis + triangular GEMM + quadratic-form ------------
// LDS map (81920 B exact -> 2 blocks/CU):
//   [0, 65536)      basis bf16 in [4p][16m] tiles, tile order [mblk(4)][kblk(16)][par(2)][kg(4)]
//                   element (p,m): byte (m>>4)<<14 | (p>>5)<<10 | ((p>>2)&1)<<9
//                                  | ((p&31)>>3)<<7 | (p&3)<<5 | (m&15 col)
//                   final: rho_buf f32[8][64] reuses [0,2KB)
//   [65536, 81920)  comp table f16 [c(32)][x,y,z,r2][8 chunks], chunk j stored at j^(c&7)
__launch_bounds__(512, 4)
__global__ void wfn_fused8(const float* __restrict__ dv,
                           const uint* __restrict__ m2aG,
                           const uint* __restrict__ m2bG,
                           const float* __restrict__ alG,
                           const short* __restrict__ dmF,
                           float* __restrict__ out) {
  __shared__ __align__(16) char smem[81920];
  const int t = threadIdx.x;
  // XCD-aware swizzle (bijective, 1024 blocks)
  const int bid = ((blockIdx.x & 7) << 7) + (blockIdx.x >> 3);
  const int n  = bid >> 6;
  const int m0 = (bid & 63) * BM;

  // ---------------- phase 1a: f16 component/r2 table ----------------
  {
    const float* dvg = dv + (size_t)(n * MS + m0) * (NA * 3);
#pragma unroll
    for (int k = 0; k < 4; ++k) {
      int idx = t + 512 * k;              // 2048 (m,c) pairs
      int m = idx >> 5, c = idx & 31;
      const float* p = dvg + (m * NA + c) * 3;
      float x = p[0], y = p[1], z = p[2];
      float r2 = fmaf(x, x, fmaf(y, y, z * z));
      uint base = TBL + (uint)c * 512u
                + ((uint)((m >> 3) ^ (c & 7)) << 4) + (uint)((m & 7) << 1);
      *(_Float16*)(smem + base)       = (_Float16)x;
      *(_Float16*)(smem + base + 128) = (_Float16)y;
      *(_Float16*)(smem + base + 256) = (_Float16)z;
      *(_Float16*)(smem + base + 384) = (_Float16)r2;
    }
  }
  __syncthreads();

  // ---------------- phase 1b: thread owns p = t, computes 64 m values ----------------
  {
    const int p = t;
    const uint ma = m2aG[n * NP + p], mb = m2bG[n * NP + p];
    const float al = alG[n * NP + p];
    const uint h0 = ma & 0xFFFFu, h1 = ma >> 16;
    const uint h2 = mb & 0x3FFFu;
    const uint d  = (mb >> 14) & 3u;
    const uint cs = (h0 >> 9) & 7u;
    const uint rh = (h0 & 0xFE00u) + 384u;
    const bool ge2 = (d >= 2), eq3 = (d == 3), eq0 = (d == 0);
    const uint wbase = ((uint)(p >> 5) << 10) + (((uint)(p >> 2) & 1u) << 9)
                     + ((((uint)p & 31u) >> 3) << 7) + (((uint)p & 3u) << 5);
#pragma unroll
    for (int j = 0; j < 8; ++j) {
      uint off = (uint)((j ^ (int)cs) << 4);
      u32x4 qr = *(const u32x4*)(smem + TBL + rh + off);
      u32x4 q0, q1, q2;
      if (!eq0) q0 = *(const u32x4*)(smem + TBL + h0 + off);   // exec-masked
      if (ge2)  q1 = *(const u32x4*)(smem + TBL + h1 + off);
      if (eq3)  q2 = *(const u32x4*)(smem + TBL + h2 + off);
      uint res[4];
#pragma unroll
      for (int w = 0; w < 4; ++w) {
        uint m_ = eq0 ? 0x3C003C00u : q0[w];
        if (ge2) m_ = pkmul(m_, q1[w]);
        if (eq3) m_ = pkmul(m_, q2[w]);
        float r2l = cvt16lo(qr[w]), r2h = cvt16hi(qr[w]);
        float a0 = al * r2l, a1 = al * r2h;
        float e0, e1;
        asm("v_exp_f32 %0, %1" : "=v"(e0) : "v"(a0));
        asm("v_exp_f32 %0, %1" : "=v"(e1) : "v"(a1));
        float v0 = cvt16lo(m_) * e0, v1 = cvt16hi(m_) * e1;
        asm("v_cvt_pk_bf16_f32 %0, %1, %2" : "=v"(res[w]) : "v"(v0), "v"(v1));
      }
      *(u32x4*)(smem + wbase + ((uint)(j >> 1) << 14) + ((uint)(j & 1) << 4))
          = *(u32x4*)res;
    }
  }
  __syncthreads();   // basis tiles visible to all waves

  // ------- triangular MFMA GEMM (upper-tri W': only kblk <= Qf>>1) + fused dot -----
  const int lane = t & 63, wv = t >> 6, li = lane & 15, kg = lane >> 4;
  const uint lane8 = (uint)lane << 3;
  const short* dmFn = dmF + (size_t)n * (32 * 16 * 512);

  f32x4 acc[4][4];
#pragma unroll
  for (int rf = 0; rf < 4; ++rf)
#pragma unroll
    for (int qf = 0; qf < 4; ++qf)
      acc[rf][qf] = (f32x4){0.f, 0.f, 0.f, 0.f};

  // interleaved q assignment balances triangular work: Qf = wv + 8*qf
  const short* bp0 = dmFn + ((size_t)((wv)      * 16) * 512) + lane * 8;
  const short* bp1 = dmFn + ((size_t)((wv + 8)  * 16) * 512) + lane * 8;
  const short* bp2 = dmFn + ((size_t)((wv + 16) * 16) * 512) + lane * 8;
  const short* bp3 = dmFn + ((size_t)((wv + 24) * 16) * 512) + lane * 8;
  const int kq0 = wv >> 1, kq1 = (wv + 8) >> 1, kq2 = (wv + 16) >> 1;
  const int kmaxw = (wv + 24) >> 1;

  for (int kblk = 0; kblk <= kmaxw; ++kblk) {
    uint ak = lane8 + ((uint)kblk << 10);
    u32x2 l0, g0, l1, g1, l2, g2, l3, g3;
    asm volatile("ds_read_b64_tr_b16 %0, %1 offset:0"     : "=v"(l0) : "v"(ak));
    asm volatile("ds_read_b64_tr_b16 %0, %1 offset:512"   : "=v"(g0) : "v"(ak));
    asm volatile("ds_read_b64_tr_b16 %0, %1 offset:16384" : "=v"(l1) : "v"(ak));
    asm volatile("ds_read_b64_tr_b16 %0, %1 offset:16896" : "=v"(g1) : "v"(ak));
    asm volatile("ds_read_b64_tr_b16 %0, %1 offset:32768" : "=v"(l2) : "v"(ak));
    asm volatile("ds_read_b64_tr_b16 %0, %1 offset:33280" : "=v"(g2) : "v"(ak));
    asm volatile("ds_read_b64_tr_b16 %0, %1 offset:49152" : "=v"(l3) : "v"(ak));
    asm volatile("ds_read_b64_tr_b16 %0, %1 offset:49664" : "=v"(g3) : "v"(ak));
    s16x8 bf0, bf1, bf2, bf3;
    if (kblk <= kq0) bf0 = *(const s16x8*)(bp0 + kblk * 512);   // wave-uniform guards
    if (kblk <= kq1) bf1 = *(const s16x8*)(bp1 + kblk * 512);
    if (kblk <= kq2) bf2 = *(const s16x8*)(bp2 + kblk * 512);
    bf3 = *(const s16x8*)(bp3 + kblk * 512);
    asm volatile("s_waitcnt lgkmcnt(0)");
    __builtin_amdgcn_sched_barrier(0);
    s16x8 af[4];
    af[0] = mkfrag(l0, g0); af[1] = mkfrag(l1, g1);
    af[2] = mkfrag(l2, g2); af[3] = mkfrag(l3, g3);
    __builtin_amdgcn_s_setprio(1);
    if (kblk <= kq0) {
#pragma unroll
      for (int rf = 0; rf < 4; ++rf)
        acc[rf][0] = __builtin_amdgcn_mfma_f32_16x16x32_bf16(af[rf], bf0, acc[rf][0], 0, 0, 0);
    }
    if (kblk <= kq1) {
#pragma unroll
      for (int rf = 0; rf < 4; ++rf)
        acc[rf][1] = __builtin_amdgcn_mfma_f32_16x16x32_bf16(af[rf], bf1, acc[rf][1], 0, 0, 0);
    }
    if (kblk <= kq2) {
#pragma unroll
      for (int rf = 0; rf < 4; ++rf)
        acc[rf][2] = __builtin_amdgcn_mfma_f32_16x16x32_bf16(af[rf], bf2, acc[rf][2], 0, 0, 0);
    }
#pragma unroll
    for (int rf = 0; rf < 4; ++rf)
      acc[rf][3] = __builtin_amdgcn_mfma_f32_16x16x32_bf16(af[rf], bf3, acc[rf][3], 0, 0, 0);
    __builtin_amdgcn_s_setprio(0);
  }

  // fused dot: part[m] = sum_q Y[m,q] * basis[m,q]; one b64 per (rf,qf) covers jj=0..3
  float part[16];
#pragma unroll
  for (int x = 0; x < 16; ++x) part[x] = 0.0f;
  uint qp[4];
#pragma unroll
  for (int qf = 0; qf < 4; ++qf) {
    int q = (wv + 8 * qf) * 16 + li;        // D col = lane&15, interleaved Qf
    qp[qf] = ((uint)(q >> 5) << 10) + (((uint)(q >> 2) & 1u) << 9)
           + (((uint)(q & 31) >> 3) << 7) + ((uint)(q & 3) << 5) + ((uint)kg << 3);
  }
#pragma unroll
  for (int rf = 0; rf < 4; ++rf) {
#pragma unroll
    for (int qf = 0; qf < 4; ++qf) {
      u32x2 dq = *(const u32x2*)(smem + ((uint)rf << 14) + qp[qf]);
      part[rf * 4 + 0] = fmaf(acc[rf][qf][0], bflo(dq[0]), part[rf * 4 + 0]);
      part[rf * 4 + 1] = fmaf(acc[rf][qf][1], bfhi(dq[0]), part[rf * 4 + 1]);
      part[rf * 4 + 2] = fmaf(acc[rf][qf][2], bflo(dq[1]), part[rf * 4 + 2]);
      part[rf * 4 + 3] = fmaf(acc[rf][qf][3], bfhi(dq[1]), part[rf * 4 + 3]);
    }
  }

  // ---------------- reduce + store (atomic-free, deterministic) ----------------
  __syncthreads();   // all basis reads done before rbuf overwrites tiles
#pragma unroll
  for (int x = 0; x < 16; ++x) {
    float v = part[x];
    v += __shfl_xor(v, 1);
    v += __shfl_xor(v, 2);
    v += __shfl_xor(v, 4);
    v += __shfl_xor(v, 8);
    part[x] = v;
  }
  float* rbuf = (float*)smem;
  if (li == 0) {
#pragma unroll
    for (int rf = 0; rf < 4; ++rf)
#pragma unroll
      for (int jj = 0; jj < 4; ++jj)
        rbuf[wv * 64 + rf * 16 + kg * 4 + jj] = part[rf * 4 + jj];
  }
  __syncthreads();
  if (t < BM) {
    float s = 0.0f;
#pragma unroll
    for (int w = 0; w < 8; ++w) s += rbuf[w * 64 + t];
    out[(size_t)n * MS + m0 + t] = s;
  }
}

extern "C" void kernel_launch(void* const* d_in, const int* in_sizes, int n_in,
                              void* d_out, int out_size, void* d_ws, size_t ws_size,
                              hipStream_t stream) {
  const float* dv      = (const float*)d_in[0];
  const int*   centers = (const int*)d_in[1];
  const float* expg    = (const float*)d_in[2];
  const int*   sym     = (const int*)d_in[3];
  const float* dm      = (const float*)d_in[4];
  float* out = (float*)d_out;

  char* ws = (char*)d_ws;
  short* dmF    = (short*)(ws + WS_DMF_OFF);
  uint*  m2a    = (uint*)(ws + WS_M2A_OFF);
  uint*  m2b    = (uint*)(ws + WS_M2B_OFF);
  float* alphaS = (float*)(ws + WS_ALPH_OFF);

  dm_pack<<<dim3(32, NMOL), 256, 0, stream>>>(dm, dmF, centers, sym, expg,
                                              m2a, m2b, alphaS);
  wfn_fused8<<<dim3(NMOL * (MS / BM)), 512, 0, stream>>>(dv, m2a, m2b, alphaS, dmF, out);
}